// Round 1
// baseline (53.759 us; speedup 1.0000x reference)
//
#include <hip/hip_runtime.h>

// Chamfer distance, B=8, N=M=4096, fp32.
// loss = (1/(B*N)) * sum over all 2*B*N entries of sqrt(min_d2)

#define BATCH 8
#define NPTS 4096
#define TQ 8            // queries per thread
#define THREADS 256
#define QB (TQ*THREADS) // 2048 queries per block
#define CHUNKS 16
#define CHUNK (NPTS/CHUNKS) // 256 db points per chunk
#define NMIN (2*BATCH*NPTS) // 65536 min-slots

__global__ void cd_init(unsigned int* __restrict__ mind2) {
    int i = blockIdx.x * blockDim.x + threadIdx.x;
    if (i < NMIN) mind2[i] = 0x7F800000u; // +inf bits
}

__global__ __launch_bounds__(THREADS) void cd_min(
        const float* __restrict__ pred,
        const float* __restrict__ targ,
        unsigned int* __restrict__ mind2) {
    const int qblk  = blockIdx.x;      // 0..1
    const int chunk = blockIdx.y;      // 0..CHUNKS-1
    const int bz    = blockIdx.z;      // dir*BATCH + b
    const int dir   = bz >> 3;
    const int b     = bz & 7;
    const float* Q  = dir ? targ : pred;
    const float* Db = dir ? pred : targ;

    __shared__ float4 sdb[CHUNK];
    const int tid = threadIdx.x;

    // stage db chunk into LDS as (x, y, z, |b|^2)
    if (tid < CHUNK) {
        const float* p = Db + ((size_t)b * NPTS + (size_t)chunk * CHUNK + tid) * 3;
        float x = p[0], y = p[1], z = p[2];
        sdb[tid] = make_float4(x, y, z, fmaf(x, x, fmaf(y, y, z * z)));
    }
    __syncthreads();

    // register-resident queries, pre-scaled by -2
    float qxm[TQ], qym[TQ], qzm[TQ], nq[TQ], m[TQ];
    const int q0 = qblk * QB + tid;  // queries q0 + k*THREADS
    #pragma unroll
    for (int k = 0; k < TQ; ++k) {
        const float* p = Q + ((size_t)b * NPTS + q0 + k * THREADS) * 3;
        float x = p[0], y = p[1], z = p[2];
        qxm[k] = -2.f * x; qym[k] = -2.f * y; qzm[k] = -2.f * z;
        nq[k]  = fmaf(x, x, fmaf(y, y, z * z));
        m[k]   = __uint_as_float(0x7F800000u);
    }

    #pragma unroll 4
    for (int j = 0; j < CHUNK; ++j) {
        float4 bp = sdb[j];   // broadcast ds_read_b128
        #pragma unroll
        for (int k = 0; k < TQ; ++k) {
            float t = fmaf(qzm[k], bp.z, bp.w);
            t = fmaf(qym[k], bp.y, t);
            t = fmaf(qxm[k], bp.x, t);
            m[k] = fminf(m[k], t);
        }
    }

    unsigned int* out = mind2 + (size_t)(dir * BATCH + b) * NPTS + q0;
    #pragma unroll
    for (int k = 0; k < TQ; ++k) {
        float d2 = fmaxf(nq[k] + m[k], 0.f);
        atomicMin(&out[k * THREADS], __float_as_uint(d2));
    }
}

__global__ __launch_bounds__(1024) void cd_finalize(
        const unsigned int* __restrict__ mind2, float* __restrict__ out) {
    __shared__ float red[1024];
    const int tid = threadIdx.x;
    float s = 0.f;
    for (int i = tid; i < NMIN; i += 1024)
        s += sqrtf(__uint_as_float(mind2[i]));
    red[tid] = s;
    __syncthreads();
    for (int off = 512; off > 0; off >>= 1) {
        if (tid < off) red[tid] += red[tid + off];
        __syncthreads();
    }
    if (tid == 0) out[0] = red[0] * (1.0f / (float)(BATCH * NPTS));
}

extern "C" void kernel_launch(void* const* d_in, const int* in_sizes, int n_in,
                              void* d_out, int out_size, void* d_ws, size_t ws_size,
                              hipStream_t stream) {
    const float* pred = (const float*)d_in[0];
    const float* targ = (const float*)d_in[1];
    unsigned int* mind2 = (unsigned int*)d_ws;   // 256 KB
    float* out = (float*)d_out;

    cd_init<<<(NMIN + 255) / 256, 256, 0, stream>>>(mind2);
    cd_min<<<dim3(NPTS / QB, CHUNKS, 2 * BATCH), THREADS, 0, stream>>>(pred, targ, mind2);
    cd_finalize<<<1, 1024, 0, stream>>>(mind2, out);
}

// Round 2
// 38.765 us; speedup vs baseline: 1.3868x; 1.3868x over previous
//
#include <hip/hip_runtime.h>

// Chamfer distance, B=8, N=M=4096, fp32.
// loss = (1/(B*N)) * sum over all 2*B*N slots of sqrt(min_d2)
//
// K1 (cd_partial): per (qblk, chunk, dir*b) block computes, for 2048 queries,
//   min over its 128-point db chunk of (|b|^2 - 2 q.b), written to P (no atomics).
// K2 (cd_reduce): per-slot min over 32 chunks, + |q|^2, sqrt, deterministic
//   fixed-point u64 atomic sum, last block writes the scalar loss.

#define BATCH 8
#define NPTS 4096
#define THREADS 256
#define TQ 8
#define QB (TQ*THREADS)        // 2048 queries per block
#define QBLKS (NPTS/QB)        // 2
#define CHUNKS 32
#define CHUNK (NPTS/CHUNKS)    // 128 db points per chunk
#define NSLOT (2*BATCH*NPTS)   // 65536
#define FIX_SCALE 4294967296.0 // 2^32

__global__ __launch_bounds__(THREADS, 4) void cd_partial(
        const float* __restrict__ pred,
        const float* __restrict__ targ,
        float* __restrict__ P,
        unsigned long long* __restrict__ hdr) {
    // zero the accumulator header once (stream order guarantees done before K2)
    if ((blockIdx.x | blockIdx.y | blockIdx.z | threadIdx.x) == 0) {
        hdr[0] = 0ull;  // fixed-point accumulator
        hdr[1] = 0ull;  // block-completion counter
    }
    const int qblk  = blockIdx.x;      // 0..QBLKS-1
    const int chunk = blockIdx.y;      // 0..CHUNKS-1
    const int dirb  = blockIdx.z;      // dir*BATCH + b, 0..15
    const int dir   = dirb >> 3;
    const int b     = dirb & 7;
    const float* Q  = dir ? targ : pred;
    const float* Db = dir ? pred : targ;

    __shared__ float4 sdb[CHUNK];
    const int tid = threadIdx.x;

    if (tid < CHUNK) {
        const float* p = Db + ((size_t)b * NPTS + (size_t)chunk * CHUNK + tid) * 3;
        float x = p[0], y = p[1], z = p[2];
        sdb[tid] = make_float4(x, y, z, fmaf(x, x, fmaf(y, y, z * z)));
    }
    __syncthreads();

    float qx[TQ], qy[TQ], qz[TQ], m[TQ];
    const int q0 = qblk * QB + tid;
    #pragma unroll
    for (int k = 0; k < TQ; ++k) {
        const float* p = Q + ((size_t)b * NPTS + q0 + k * THREADS) * 3;
        qx[k] = -2.f * p[0]; qy[k] = -2.f * p[1]; qz[k] = -2.f * p[2];
        m[k]  = __uint_as_float(0x7F800000u);
    }

    #pragma unroll 4
    for (int j = 0; j < CHUNK; j += 2) {
        float4 b0 = sdb[j];
        float4 b1 = sdb[j + 1];
        #pragma unroll
        for (int k = 0; k < TQ; ++k) {
            float t0 = fmaf(qz[k], b0.z, b0.w);
            t0 = fmaf(qy[k], b0.y, t0);
            t0 = fmaf(qx[k], b0.x, t0);
            float t1 = fmaf(qz[k], b1.z, b1.w);
            t1 = fmaf(qy[k], b1.y, t1);
            t1 = fmaf(qx[k], b1.x, t1);
            m[k] = fminf(m[k], fminf(t0, t1));  // -> v_min3_f32
        }
    }

    float* out = P + (size_t)chunk * NSLOT + (size_t)dirb * NPTS + q0;
    #pragma unroll
    for (int k = 0; k < TQ; ++k) out[k * THREADS] = m[k];
}

__global__ __launch_bounds__(256) void cd_reduce(
        const float* __restrict__ pred,
        const float* __restrict__ targ,
        const float* __restrict__ P,
        unsigned long long* __restrict__ hdr,
        float* __restrict__ out) {
    const int tid  = threadIdx.x;
    const int slot = blockIdx.x * 256 + tid;   // 0..NSLOT-1
    const int dirb = slot >> 12;
    const int q    = slot & (NPTS - 1);
    const int dir  = dirb >> 3;
    const int b    = dirb & 7;

    const float* p = (dir ? targ : pred) + ((size_t)b * NPTS + q) * 3;
    float x = p[0], y = p[1], z = p[2];
    float nq = fmaf(x, x, fmaf(y, y, z * z));

    float m = __uint_as_float(0x7F800000u);
    #pragma unroll
    for (int c = 0; c < CHUNKS; c += 2)
        m = fminf(m, fminf(P[(size_t)c * NSLOT + slot],
                           P[(size_t)(c + 1) * NSLOT + slot]));

    float d = sqrtf(fmaxf(nq + m, 0.f));

    // wave reduction (64 lanes)
    float s = d;
    #pragma unroll
    for (int off = 32; off > 0; off >>= 1) s += __shfl_down(s, off);
    __shared__ float wsum[4];
    if ((tid & 63) == 0) wsum[tid >> 6] = s;
    __syncthreads();

    if (tid == 0) {
        float bs = wsum[0] + wsum[1] + wsum[2] + wsum[3];
        unsigned long long fx = (unsigned long long)((double)bs * FIX_SCALE);
        atomicAdd(hdr, fx);
        __threadfence();
        unsigned int old = atomicAdd((unsigned int*)(hdr + 1), 1u);
        if (old == gridDim.x - 1) {
            unsigned long long tot = atomicAdd(hdr, 0ull);
            out[0] = (float)(((double)tot / FIX_SCALE) / (double)(BATCH * NPTS));
        }
    }
}

extern "C" void kernel_launch(void* const* d_in, const int* in_sizes, int n_in,
                              void* d_out, int out_size, void* d_ws, size_t ws_size,
                              hipStream_t stream) {
    const float* pred = (const float*)d_in[0];
    const float* targ = (const float*)d_in[1];
    unsigned long long* hdr = (unsigned long long*)d_ws;            // 16 B header
    float* P = (float*)((char*)d_ws + 64);                          // 8 MB partials
    float* out = (float*)d_out;

    cd_partial<<<dim3(QBLKS, CHUNKS, 2 * BATCH), THREADS, 0, stream>>>(pred, targ, P, hdr);
    cd_reduce<<<NSLOT / 256, 256, 0, stream>>>(pred, targ, P, hdr, out);
}